// Round 13
// baseline (137.557 us; speedup 1.0000x reference)
//
#include <hip/hip_runtime.h>
#include <hip/hip_bf16.h>

typedef __bf16 bf16;
typedef __bf16 bf16x8 __attribute__((ext_vector_type(8)));
typedef __bf16 bf16x4 __attribute__((ext_vector_type(4)));
typedef float  f32x4  __attribute__((ext_vector_type(4)));
typedef float  f32x16 __attribute__((ext_vector_type(16)));
typedef unsigned int u32x4 __attribute__((ext_vector_type(4)));

static constexpr int SDIM = 2048;
static constexpr int EDIM = 512;
static constexpr int HDIM = 64;

typedef __attribute__((address_space(1))) const void* gptr_t;
typedef __attribute__((address_space(3))) void*       lptr_t;

__device__ __forceinline__ void gl_lds16(const bf16* g, bf16* l) {
  __builtin_amdgcn_global_load_lds((gptr_t)g, (lptr_t)l, 16, 0, 0);
}

#if __has_builtin(__builtin_amdgcn_exp2f)
#define EXP2F(x) __builtin_amdgcn_exp2f(x)
#else
#define EXP2F(x) exp2f(x)
#endif

__device__ __forceinline__ bf16x8 pack8(f32x4 a, f32x4 b) {
  bf16x8 r;
  r[0] = (bf16)a[0]; r[1] = (bf16)a[1]; r[2] = (bf16)a[2]; r[3] = (bf16)a[3];
  r[4] = (bf16)b[0]; r[5] = (bf16)b[1]; r[6] = (bf16)b[2]; r[7] = (bf16)b[3];
  return r;
}

__device__ __forceinline__ unsigned cvtpk_bf16(float a, float b) {
  unsigned r;
  asm("v_cvt_pk_bf16_f32 %0, %1, %2" : "=v"(r) : "v"(a), "v"(b));
  return r;
}

// ---------------------------------------------------------------------------
// Kernel A: W (f32 [512][64]) -> Wt (bf16 [64][512]) via LDS transpose.
// Wq scaled by 0.125*log2(e): scores exit QK^T in log2 units (bare exp2).
// ---------------------------------------------------------------------------
__global__ __launch_bounds__(256) void wt_kernel(const float* __restrict__ Wq,
                                                 const float* __restrict__ Wk,
                                                 const float* __restrict__ Wv,
                                                 bf16* __restrict__ Wt) {
  __shared__ float lds[64][65];
  const int mat = blockIdx.x >> 3;
  const int et  = blockIdx.x & 7;
  const float* W = (mat == 0) ? Wq : ((mat == 1) ? Wk : Wv);
  const float scale = (mat == 0) ? 0.18033688f : 1.0f;   // 0.125 * log2(e)
  const int t  = threadIdx.x;
  const int er = t >> 2;
  const int c4 = (t & 3) * 16;
#pragma unroll
  for (int j = 0; j < 4; ++j) {
    f32x4 v = *(const f32x4*)(W + (size_t)(et * 64 + er) * HDIM + c4 + j * 4);
    lds[er][c4 + j * 4 + 0] = v[0]; lds[er][c4 + j * 4 + 1] = v[1];
    lds[er][c4 + j * 4 + 2] = v[2]; lds[er][c4 + j * 4 + 3] = v[3];
  }
  __syncthreads();
  const int h  = t >> 2;
  const int ec = (t & 3) * 16;
  bf16x8 o0, o1;
#pragma unroll
  for (int j = 0; j < 8; ++j) o0[j] = (bf16)(lds[ec + j][h] * scale);
#pragma unroll
  for (int j = 0; j < 8; ++j) o1[j] = (bf16)(lds[ec + 8 + j][h] * scale);
  bf16* dst = Wt + mat * (HDIM * EDIM) + (size_t)h * EDIM + et * 64 + ec;
  *(bf16x8*)dst = o0;
  *(bf16x8*)(dst + 8) = o1;
}

// ---------------------------------------------------------------------------
// Kernel B: fused QKV projection (R2 counted-vmcnt structure; ~10us, at its
// HBM roofline per R7 diagnosis — unchanged).
// ---------------------------------------------------------------------------
__global__ __launch_bounds__(256) void proj_kernel(const float* __restrict__ x,
                                                   const bf16* __restrict__ Wt,
                                                   const int* __restrict__ lens,
                                                   bf16* __restrict__ qo,
                                                   bf16* __restrict__ ko,
                                                   bf16* __restrict__ vT) {
  __shared__ __align__(16) bf16 wbuf[2][192 * 64];   // [m*64+h][e 0..63] swz
  const int tid  = threadIdx.x;
  const int wave = tid >> 6;
  const int lane = tid & 63;
  const int quad = lane >> 4;
  const int l16  = lane & 15;
  const int rowbase = blockIdx.x * 64 + wave * 16;
  const int b = blockIdx.x >> 5;                     // 32 blocks per batch
  const float* xrow = x + (size_t)(rowbase + l16) * EDIM + quad * 8;
  const int srow   = lane >> 3;                      // 0..7 (row within 8-block)
  const int schunk = (lane & 7) ^ srow;              // global chunk to fetch

  #define WSTAGE(ck, buf) { _Pragma("unroll")                                  \
    for (int i6 = 0; i6 < 6; ++i6) {                                           \
      const int R0 = (wave * 6 + i6) * 8;                                      \
      gl_lds16(Wt + (size_t)(R0 + srow) * EDIM + (ck) * 64 + schunk * 8,       \
               &(buf)[R0 * 64]); } }

  f32x4 acc[3][4];
#pragma unroll
  for (int m = 0; m < 3; ++m)
#pragma unroll
    for (int nt = 0; nt < 4; ++nt) acc[m][nt] = (f32x4){0.f, 0.f, 0.f, 0.f};

  #define WCOMPUTE(buf, eo4, afrag) { _Pragma("unroll")                        \
    for (int m = 0; m < 3; ++m) { _Pragma("unroll")                            \
      for (int nt = 0; nt < 4; ++nt) {                                         \
        bf16x8 bfv = *(const bf16x8*)(&(buf)[(m * 64 + nt * 16 + l16) * 64 +   \
                                             ((((eo4) + quad) ^ (l16 & 7)) * 8)]); \
        acc[m][nt] = __builtin_amdgcn_mfma_f32_16x16x32_bf16(afrag, bfv, acc[m][nt], 0, 0, 0); } } }

  // prologue: stage chunk 0 (6 gl_lds), then x(0) and x(1) (8 loads).
  WSTAGE(0, wbuf[0]);
  __builtin_amdgcn_sched_barrier(0);
  f32x4 c0 = *(const f32x4*)(xrow);
  f32x4 c1 = *(const f32x4*)(xrow + 4);
  f32x4 c2 = *(const f32x4*)(xrow + 32);
  f32x4 c3 = *(const f32x4*)(xrow + 36);
  f32x4 n0 = *(const f32x4*)(xrow + 64);
  f32x4 n1 = *(const f32x4*)(xrow + 68);
  f32x4 n2 = *(const f32x4*)(xrow + 96);
  f32x4 n3 = *(const f32x4*)(xrow + 100);
  __builtin_amdgcn_sched_barrier(0);
  asm volatile("s_waitcnt vmcnt(8)" ::: "memory");
  __builtin_amdgcn_s_barrier();
  __builtin_amdgcn_sched_barrier(0);

#pragma unroll
  for (int ck = 0; ck < 8; ++ck) {
    const int cs = (ck < 7) ? (ck + 1) : 7;
    WSTAGE(cs, wbuf[(ck + 1) & 1]);
    __builtin_amdgcn_sched_barrier(0);
    const int kf = (ck < 6) ? (ck + 2) : 7;
    f32x4 m0 = *(const f32x4*)(xrow + kf * 64);
    f32x4 m1 = *(const f32x4*)(xrow + kf * 64 + 4);
    f32x4 m2 = *(const f32x4*)(xrow + kf * 64 + 32);
    f32x4 m3 = *(const f32x4*)(xrow + kf * 64 + 36);
    __builtin_amdgcn_sched_barrier(0);
    bf16x8 a = pack8(c0, c1);
    WCOMPUTE(wbuf[ck & 1], 0, a);
    a = pack8(c2, c3);
    WCOMPUTE(wbuf[ck & 1], 4, a);
    c0 = n0; c1 = n1; c2 = n2; c3 = n3;
    n0 = m0; n1 = m1; n2 = m2; n3 = m3;
    asm volatile("s_waitcnt vmcnt(4)" ::: "memory");
    __builtin_amdgcn_s_barrier();
    __builtin_amdgcn_sched_barrier(0);
  }

  int odd_or = 0;
#pragma unroll
  for (int i = 1; i < 16; i += 2) odd_or |= lens[i];
  const int len = (odd_or == 0) ? lens[2 * b] : lens[b];

#pragma unroll
  for (int nt = 0; nt < 4; ++nt) {
    const int h = nt * 16 + l16;
    bf16x4 vv;
#pragma unroll
    for (int r = 0; r < 4; ++r) {
      const int row = rowbase + quad * 4 + r;        // C-layout row = quad*4+reg
      const int s = row & (SDIM - 1);
      const bool pad = (s >= len);
      qo[(size_t)row * HDIM + h] = (bf16)(pad ? 0.f : acc[0][nt][r]);
      ko[(size_t)row * HDIM + h] = (bf16)(pad ? 0.f : acc[1][nt][r]);
      vv[r] = (bf16)acc[2][nt][r];                   // v NOT masked
    }
    *(bf16x4*)(vT + ((size_t)b * HDIM + h) * SDIM + (rowbase & (SDIM - 1)) + quad * 4) = vv;
  }
  #undef WSTAGE
  #undef WCOMPUTE
}

// ---------------------------------------------------------------------------
// Kernel C: flash attention — 8-wave R12 structure + chain-shortening bundle:
// (1) QK accumulator split into two independent MFMA chains (st0: e 0..31,
//     st1: e 32..63), summed at exp2 input — halves the 4-deep serial
//     MFMA dependency that R12's counters showed as the residual cost.
// (2) vf LDS reads hoisted before the QK MFMAs: compiler's lgkmcnt leaves
//     them in flight under QK+softmax, so PV starts without an LDS wait.
// Staging, barriers, combine, setprio unchanged from R12 (133.4us best).
// ---------------------------------------------------------------------------
__global__ __launch_bounds__(512, 4) void attn_kernel(const bf16* __restrict__ qb,
                                                      const bf16* __restrict__ kb,
                                                      const bf16* __restrict__ vT,
                                                      float* __restrict__ out) {
  __shared__ __align__(16) bf16 Kbuf[2][2][64 * 64];   // [dbuf][key-half][key][e]
  __shared__ __align__(16) bf16 Vbuf[2][2][64 * 64];   // [dbuf][key-half][h][t]
  const int tid  = threadIdx.x;
  const int wave = tid >> 6;          // 0..7
  const int lane = tid & 63;
  const int hi   = lane >> 5;
  const int l32  = lane & 31;
  const int iq   = wave & 1;          // q half (0/1)
  const int jk   = (wave >> 1) & 1;   // key half (0/1)
  const int sub  = wave >> 2;         // 32-key sub-window (0/1)
  const int xcd = blockIdx.x & 7;
  const int jj  = blockIdx.x >> 3;
  const int b   = xcd * 2 + (jj >> 5);
  const int qbase = (jj & 31) * 64 + iq * 32;
  const bf16* q0 = qb + (size_t)b * SDIM * HDIM;
  const bf16* k0 = kb + (size_t)b * SDIM * HDIM;
  const bf16* v0 = vT + (size_t)b * HDIM * SDIM;
  const int srow   = lane >> 3;            // 0..7
  const int schunk = (lane & 7) ^ srow;    // pre-swizzled source 16B chunk
  const int rswz   = (l32 & 7) << 4;       // read-side XOR (row&7)<<4

  // Q B-frags: lane holds Q[qbase+l32][c*16 + hi*8 .. +8]  (global, L2-hot)
  bf16x8 qf[4];
#pragma unroll
  for (int c = 0; c < 4; ++c)
    qf[c] = *(const bf16x8*)(q0 + (size_t)(qbase + l32) * HDIM + c * 16 + hi * 8);

  f32x16 O[2];
#pragma unroll
  for (int ht = 0; ht < 2; ++ht)
#pragma unroll
    for (int r = 0; r < 16; ++r) O[ht][r] = 0.f;
  float l_acc = 0.f;

  // Staging with 8 waves, 4 gl_lds each:
  // waves 0-3: K (half = (w>>1)&1, rows (w&1)*32..+32)
  // waves 4-7: V (half = (w>>1)&1, h-rows (w&1)*32..+32)
  #define STAGE(sidx, db) {                                                    \
    const int half_ = (wave >> 1) & 1;                                         \
    const int rb_   = (wave & 1) * 32;                                         \
    const int key0_ = half_ * 1024 + (sidx) * 64;                              \
    if (wave < 4) {                                                            \
      const bf16* gk = k0 + (size_t)(key0_ + rb_ + srow) * HDIM + schunk * 8;  \
      bf16* lk = &Kbuf[db][half_][rb_ * 64];                                   \
      _Pragma("unroll")                                                        \
      for (int j4 = 0; j4 < 4; ++j4)                                           \
        gl_lds16(gk + (size_t)j4 * 8 * HDIM, lk + j4 * 8 * 64);                \
    } else {                                                                   \
      const bf16* gv = v0 + (size_t)(rb_ + srow) * SDIM + key0_ + schunk * 8;  \
      bf16* lv = &Vbuf[db][half_][rb_ * 64];                                   \
      _Pragma("unroll")                                                        \
      for (int j4 = 0; j4 < 4; ++j4)                                           \
        gl_lds16(gv + (size_t)j4 * 8 * SDIM, lv + j4 * 8 * 64);                \
    }                                                                          \
  }

  STAGE(0, 0);
#pragma unroll 2
  for (int s = 0; s < 16; ++s) {
    __syncthreads();                       // buf[s&1] staged
    if (s + 1 < 16) STAGE(s + 1, (s + 1) & 1);
    const bf16* KB = &Kbuf[s & 1][jk][0];
    const bf16* VB = &Vbuf[s & 1][jk][0];

    // K frags (4 b128) then V frags (4 b128) — vf issued EARLY so its lgkm
    // latency hides under the QK MFMAs + softmax VALU below.
    const int krow = sub * 32 + l32;
    bf16x8 kf0 = *(const bf16x8*)((const char*)KB + krow * 128 + ((0 * 32 + hi * 16) ^ rswz));
    bf16x8 kf1 = *(const bf16x8*)((const char*)KB + krow * 128 + ((1 * 32 + hi * 16) ^ rswz));
    bf16x8 kf2 = *(const bf16x8*)((const char*)KB + krow * 128 + ((2 * 32 + hi * 16) ^ rswz));
    bf16x8 kf3 = *(const bf16x8*)((const char*)KB + krow * 128 + ((3 * 32 + hi * 16) ^ rswz));
    bf16x8 vf00 = *(const bf16x8*)((const char*)VB + (0 * 32 + l32) * 128 +
                                   ((sub * 64 + 0 * 32 + hi * 16) ^ rswz));
    bf16x8 vf01 = *(const bf16x8*)((const char*)VB + (0 * 32 + l32) * 128 +
                                   ((sub * 64 + 1 * 32 + hi * 16) ^ rswz));
    bf16x8 vf10 = *(const bf16x8*)((const char*)VB + (1 * 32 + l32) * 128 +
                                   ((sub * 64 + 0 * 32 + hi * 16) ^ rswz));
    bf16x8 vf11 = *(const bf16x8*)((const char*)VB + (1 * 32 + l32) * 128 +
                                   ((sub * 64 + 1 * 32 + hi * 16) ^ rswz));

    // QK^T: two INDEPENDENT accumulator chains (halved serial depth)
    f32x16 st0, st1;
#pragma unroll
    for (int r = 0; r < 16; ++r) { st0[r] = 0.f; st1[r] = 0.f; }
    __builtin_amdgcn_s_setprio(1);
    st0 = __builtin_amdgcn_mfma_f32_32x32x16_bf16(kf0, qf[0], st0, 0, 0, 0);
    st1 = __builtin_amdgcn_mfma_f32_32x32x16_bf16(kf2, qf[2], st1, 0, 0, 0);
    st0 = __builtin_amdgcn_mfma_f32_32x32x16_bf16(kf1, qf[1], st0, 0, 0, 0);
    st1 = __builtin_amdgcn_mfma_f32_32x32x16_bf16(kf3, qf[3], st1, 0, 0, 0);
    __builtin_amdgcn_s_setprio(0);
    // lane holds P[key = sub*32 + (r&3)+8*(r>>2)+4*hi][q=l32], log2 units
    float p[16];
#pragma unroll
    for (int r = 0; r < 16; ++r) p[r] = EXP2F(st0[r] + st1[r]);
    {
      float s0 = (p[0] + p[1]) + (p[2] + p[3]);
      float s1 = (p[4] + p[5]) + (p[6] + p[7]);
      float s2 = (p[8] + p[9]) + (p[10] + p[11]);
      float s3 = (p[12] + p[13]) + (p[14] + p[15]);
      l_acc += (s0 + s1) + (s2 + s3);
    }
    // in-register transpose: cvt_pk pairs, swap row halves across lane+-32.
    bf16x8 pa0, pa1;
    {
      unsigned u0 = cvtpk_bf16(p[0], p[1]);
      unsigned u1 = cvtpk_bf16(p[2], p[3]);
      unsigned u2 = cvtpk_bf16(p[4], p[5]);
      unsigned u3 = cvtpk_bf16(p[6], p[7]);
      asm("v_permlane32_swap_b32 %0, %1" : "+v"(u0), "+v"(u2));
      asm("v_permlane32_swap_b32 %0, %1" : "+v"(u1), "+v"(u3));
      union { u32x4 u; bf16x8 v; } f0;
      f0.u[0] = u0; f0.u[1] = u1; f0.u[2] = u2; f0.u[3] = u3;
      pa0 = f0.v;
      unsigned u4 = cvtpk_bf16(p[8],  p[9]);
      unsigned u5 = cvtpk_bf16(p[10], p[11]);
      unsigned u6 = cvtpk_bf16(p[12], p[13]);
      unsigned u7 = cvtpk_bf16(p[14], p[15]);
      asm("v_permlane32_swap_b32 %0, %1" : "+v"(u4), "+v"(u6));
      asm("v_permlane32_swap_b32 %0, %1" : "+v"(u5), "+v"(u7));
      union { u32x4 u; bf16x8 v; } f1;
      f1.u[0] = u4; f1.u[1] = u5; f1.u[2] = u6; f1.u[3] = u7;
      pa1 = f1.v;
    }
    // PV over the 32-key sub-window (two independent O chains)
    __builtin_amdgcn_s_setprio(1);
    O[0] = __builtin_amdgcn_mfma_f32_32x32x16_bf16(pa0, vf00, O[0], 0, 0, 0);
    O[1] = __builtin_amdgcn_mfma_f32_32x32x16_bf16(pa0, vf10, O[1], 0, 0, 0);
    O[0] = __builtin_amdgcn_mfma_f32_32x32x16_bf16(pa1, vf01, O[0], 0, 0, 0);
    O[1] = __builtin_amdgcn_mfma_f32_32x32x16_bf16(pa1, vf11, O[1], 0, 0, 0);
    __builtin_amdgcn_s_setprio(0);
  }

  // lane l and l+32 cover complementary key rows for the same q
  l_acc += __shfl_xor(l_acc, 32);

  // -------- 4-way cross-group combine through freed K/V LDS --------
  const int grp = wave >> 1;
  __syncthreads();                       // all waves done with K/V buffers
  if (grp != 0) {
    float* pb = (grp == 1) ? (float*)&Kbuf[0][0][0]
              : (grp == 2) ? (float*)&Kbuf[1][0][0]
                           : (float*)&Vbuf[0][0][0];
#pragma unroll
    for (int r = 0; r < 16; ++r) {
      const int qrow = (r & 3) + 8 * (r >> 2) + 4 * hi;
      pb[(iq * 32 + qrow) * 64 + 0 * 32 + l32] = O[0][r];
      pb[(iq * 32 + qrow) * 64 + 1 * 32 + l32] = O[1][r];
    }
    if (hi == 0)
      ((float*)&Vbuf[1][0][0])[(grp - 1) * 64 + iq * 32 + l32] = l_acc;
  }
  __syncthreads();
  if (grp == 0) {
    const float* p1 = (const float*)&Kbuf[0][0][0];
    const float* p2 = (const float*)&Kbuf[1][0][0];
    const float* p3 = (const float*)&Vbuf[0][0][0];
    const float* lp = (const float*)&Vbuf[1][0][0];
    const float lt = l_acc + lp[0 * 64 + iq * 32 + l32]
                   + lp[1 * 64 + iq * 32 + l32] + lp[2 * 64 + iq * 32 + l32];
    const float inv_own = 1.0f / lt;       // lane holds total l for q=l32
#pragma unroll
    for (int r = 0; r < 16; ++r) {
      const int qrow = (r & 3) + 8 * (r >> 2) + 4 * hi;
      const float inv = __shfl(inv_own, qrow);
#pragma unroll
      for (int ht = 0; ht < 2; ++ht) {
        const int idx = (iq * 32 + qrow) * 64 + ht * 32 + l32;
        const float val = (O[ht][r] + p1[idx] + p2[idx] + p3[idx]) * inv;
        out[((size_t)b * SDIM + qbase + qrow) * HDIM + ht * 32 + l32] = val;
      }
    }
  }
  #undef STAGE
}

// ---------------------------------------------------------------------------
extern "C" void kernel_launch(void* const* d_in, const int* in_sizes, int n_in,
                              void* d_out, int out_size, void* d_ws, size_t ws_size,
                              hipStream_t stream) {
  (void)in_sizes; (void)n_in; (void)out_size; (void)ws_size;
  const float* x  = (const float*)d_in[0];
  const int*   sl = (const int*)d_in[1];
  const float* Wq = (const float*)d_in[2];
  const float* Wk = (const float*)d_in[3];
  const float* Wv = (const float*)d_in[4];
  float* out = (float*)d_out;

  char* ws = (char*)d_ws;
  bf16* Wt = (bf16*)(ws);                              // 192 KB
  bf16* qb = (bf16*)(ws + (256 << 10));                // 4 MB
  bf16* kb = (bf16*)(ws + (256 << 10) + (4 << 20));    // 4 MB
  bf16* vT = (bf16*)(ws + (256 << 10) + (8 << 20));    // 4 MB ([B][64][S])

  wt_kernel  <<<24,  256, 0, stream>>>(Wq, Wk, Wv, Wt);
  proj_kernel<<<512, 256, 0, stream>>>(x, Wt, sl, qb, kb, vT);
  attn_kernel<<<512, 512, 0, stream>>>(qb, kb, vT, out);
}

// Round 14
// 133.206 us; speedup vs baseline: 1.0327x; 1.0327x over previous
//
#include <hip/hip_runtime.h>
#include <hip/hip_bf16.h>

typedef __bf16 bf16;
typedef __bf16 bf16x8 __attribute__((ext_vector_type(8)));
typedef __bf16 bf16x4 __attribute__((ext_vector_type(4)));
typedef float  f32x4  __attribute__((ext_vector_type(4)));
typedef float  f32x16 __attribute__((ext_vector_type(16)));
typedef unsigned int u32x4 __attribute__((ext_vector_type(4)));

static constexpr int SDIM = 2048;
static constexpr int EDIM = 512;
static constexpr int HDIM = 64;

typedef __attribute__((address_space(1))) const void* gptr_t;
typedef __attribute__((address_space(3))) void*       lptr_t;

__device__ __forceinline__ void gl_lds16(const bf16* g, bf16* l) {
  __builtin_amdgcn_global_load_lds((gptr_t)g, (lptr_t)l, 16, 0, 0);
}

#if __has_builtin(__builtin_amdgcn_exp2f)
#define EXP2F(x) __builtin_amdgcn_exp2f(x)
#else
#define EXP2F(x) exp2f(x)
#endif

__device__ __forceinline__ bf16x8 pack8(f32x4 a, f32x4 b) {
  bf16x8 r;
  r[0] = (bf16)a[0]; r[1] = (bf16)a[1]; r[2] = (bf16)a[2]; r[3] = (bf16)a[3];
  r[4] = (bf16)b[0]; r[5] = (bf16)b[1]; r[6] = (bf16)b[2]; r[7] = (bf16)b[3];
  return r;
}

__device__ __forceinline__ unsigned cvtpk_bf16(float a, float b) {
  unsigned r;
  asm("v_cvt_pk_bf16_f32 %0, %1, %2" : "=v"(r) : "v"(a), "v"(b));
  return r;
}

// ---------------------------------------------------------------------------
// Kernel A: W (f32 [512][64]) -> Wt (bf16 [64][512]) via LDS transpose.
// Wq scaled by 0.125*log2(e): scores exit QK^T in log2 units (bare exp2).
// ---------------------------------------------------------------------------
__global__ __launch_bounds__(256) void wt_kernel(const float* __restrict__ Wq,
                                                 const float* __restrict__ Wk,
                                                 const float* __restrict__ Wv,
                                                 bf16* __restrict__ Wt) {
  __shared__ float lds[64][65];
  const int mat = blockIdx.x >> 3;
  const int et  = blockIdx.x & 7;
  const float* W = (mat == 0) ? Wq : ((mat == 1) ? Wk : Wv);
  const float scale = (mat == 0) ? 0.18033688f : 1.0f;   // 0.125 * log2(e)
  const int t  = threadIdx.x;
  const int er = t >> 2;
  const int c4 = (t & 3) * 16;
#pragma unroll
  for (int j = 0; j < 4; ++j) {
    f32x4 v = *(const f32x4*)(W + (size_t)(et * 64 + er) * HDIM + c4 + j * 4);
    lds[er][c4 + j * 4 + 0] = v[0]; lds[er][c4 + j * 4 + 1] = v[1];
    lds[er][c4 + j * 4 + 2] = v[2]; lds[er][c4 + j * 4 + 3] = v[3];
  }
  __syncthreads();
  const int h  = t >> 2;
  const int ec = (t & 3) * 16;
  bf16x8 o0, o1;
#pragma unroll
  for (int j = 0; j < 8; ++j) o0[j] = (bf16)(lds[ec + j][h] * scale);
#pragma unroll
  for (int j = 0; j < 8; ++j) o1[j] = (bf16)(lds[ec + 8 + j][h] * scale);
  bf16* dst = Wt + mat * (HDIM * EDIM) + (size_t)h * EDIM + et * 64 + ec;
  *(bf16x8*)dst = o0;
  *(bf16x8*)(dst + 8) = o1;
}

// ---------------------------------------------------------------------------
// Kernel B: fused QKV projection (R2 counted-vmcnt structure; ~10us, at its
// HBM roofline per R7 diagnosis — unchanged).
// ---------------------------------------------------------------------------
__global__ __launch_bounds__(256) void proj_kernel(const float* __restrict__ x,
                                                   const bf16* __restrict__ Wt,
                                                   const int* __restrict__ lens,
                                                   bf16* __restrict__ qo,
                                                   bf16* __restrict__ ko,
                                                   bf16* __restrict__ vT) {
  __shared__ __align__(16) bf16 wbuf[2][192 * 64];   // [m*64+h][e 0..63] swz
  const int tid  = threadIdx.x;
  const int wave = tid >> 6;
  const int lane = tid & 63;
  const int quad = lane >> 4;
  const int l16  = lane & 15;
  const int rowbase = blockIdx.x * 64 + wave * 16;
  const int b = blockIdx.x >> 5;                     // 32 blocks per batch
  const float* xrow = x + (size_t)(rowbase + l16) * EDIM + quad * 8;
  const int srow   = lane >> 3;                      // 0..7 (row within 8-block)
  const int schunk = (lane & 7) ^ srow;              // global chunk to fetch

  #define WSTAGE(ck, buf) { _Pragma("unroll")                                  \
    for (int i6 = 0; i6 < 6; ++i6) {                                           \
      const int R0 = (wave * 6 + i6) * 8;                                      \
      gl_lds16(Wt + (size_t)(R0 + srow) * EDIM + (ck) * 64 + schunk * 8,       \
               &(buf)[R0 * 64]); } }

  f32x4 acc[3][4];
#pragma unroll
  for (int m = 0; m < 3; ++m)
#pragma unroll
    for (int nt = 0; nt < 4; ++nt) acc[m][nt] = (f32x4){0.f, 0.f, 0.f, 0.f};

  #define WCOMPUTE(buf, eo4, afrag) { _Pragma("unroll")                        \
    for (int m = 0; m < 3; ++m) { _Pragma("unroll")                            \
      for (int nt = 0; nt < 4; ++nt) {                                         \
        bf16x8 bfv = *(const bf16x8*)(&(buf)[(m * 64 + nt * 16 + l16) * 64 +   \
                                             ((((eo4) + quad) ^ (l16 & 7)) * 8)]); \
        acc[m][nt] = __builtin_amdgcn_mfma_f32_16x16x32_bf16(afrag, bfv, acc[m][nt], 0, 0, 0); } } }

  // prologue: stage chunk 0 (6 gl_lds), then x(0) and x(1) (8 loads).
  WSTAGE(0, wbuf[0]);
  __builtin_amdgcn_sched_barrier(0);
  f32x4 c0 = *(const f32x4*)(xrow);
  f32x4 c1 = *(const f32x4*)(xrow + 4);
  f32x4 c2 = *(const f32x4*)(xrow + 32);
  f32x4 c3 = *(const f32x4*)(xrow + 36);
  f32x4 n0 = *(const f32x4*)(xrow + 64);
  f32x4 n1 = *(const f32x4*)(xrow + 68);
  f32x4 n2 = *(const f32x4*)(xrow + 96);
  f32x4 n3 = *(const f32x4*)(xrow + 100);
  __builtin_amdgcn_sched_barrier(0);
  asm volatile("s_waitcnt vmcnt(8)" ::: "memory");
  __builtin_amdgcn_s_barrier();
  __builtin_amdgcn_sched_barrier(0);

#pragma unroll
  for (int ck = 0; ck < 8; ++ck) {
    const int cs = (ck < 7) ? (ck + 1) : 7;
    WSTAGE(cs, wbuf[(ck + 1) & 1]);
    __builtin_amdgcn_sched_barrier(0);
    const int kf = (ck < 6) ? (ck + 2) : 7;
    f32x4 m0 = *(const f32x4*)(xrow + kf * 64);
    f32x4 m1 = *(const f32x4*)(xrow + kf * 64 + 4);
    f32x4 m2 = *(const f32x4*)(xrow + kf * 64 + 32);
    f32x4 m3 = *(const f32x4*)(xrow + kf * 64 + 36);
    __builtin_amdgcn_sched_barrier(0);
    bf16x8 a = pack8(c0, c1);
    WCOMPUTE(wbuf[ck & 1], 0, a);
    a = pack8(c2, c3);
    WCOMPUTE(wbuf[ck & 1], 4, a);
    c0 = n0; c1 = n1; c2 = n2; c3 = n3;
    n0 = m0; n1 = m1; n2 = m2; n3 = m3;
    asm volatile("s_waitcnt vmcnt(4)" ::: "memory");
    __builtin_amdgcn_s_barrier();
    __builtin_amdgcn_sched_barrier(0);
  }

  int odd_or = 0;
#pragma unroll
  for (int i = 1; i < 16; i += 2) odd_or |= lens[i];
  const int len = (odd_or == 0) ? lens[2 * b] : lens[b];

#pragma unroll
  for (int nt = 0; nt < 4; ++nt) {
    const int h = nt * 16 + l16;
    bf16x4 vv;
#pragma unroll
    for (int r = 0; r < 4; ++r) {
      const int row = rowbase + quad * 4 + r;        // C-layout row = quad*4+reg
      const int s = row & (SDIM - 1);
      const bool pad = (s >= len);
      qo[(size_t)row * HDIM + h] = (bf16)(pad ? 0.f : acc[0][nt][r]);
      ko[(size_t)row * HDIM + h] = (bf16)(pad ? 0.f : acc[1][nt][r]);
      vv[r] = (bf16)acc[2][nt][r];                   // v NOT masked
    }
    *(bf16x4*)(vT + ((size_t)b * HDIM + h) * SDIM + (rowbase & (SDIM - 1)) + quad * 4) = vv;
  }
  #undef WSTAGE
  #undef WCOMPUTE
}

// ---------------------------------------------------------------------------
// Kernel C: flash attention — 8-wave / 512-thread R12 structure (BEST: 133.4).
// R13 post-mortem: chain-split + vf-hoist exceeded the 128-VGPR cap of
// launch_bounds(512,4) -> spills; reverted byte-for-byte to R12.
// 8 waves = 2 q-halves x 2 key-halves x 2 sub-windows; per-wave per step:
// 4 QK + 4 PV MFMAs, 16 exp2, 8 b128. 2 blocks/CU x 8 waves = 4 waves/SIMD.
// ---------------------------------------------------------------------------
__global__ __launch_bounds__(512, 4) void attn_kernel(const bf16* __restrict__ qb,
                                                      const bf16* __restrict__ kb,
                                                      const bf16* __restrict__ vT,
                                                      float* __restrict__ out) {
  __shared__ __align__(16) bf16 Kbuf[2][2][64 * 64];   // [dbuf][key-half][key][e]
  __shared__ __align__(16) bf16 Vbuf[2][2][64 * 64];   // [dbuf][key-half][h][t]
  const int tid  = threadIdx.x;
  const int wave = tid >> 6;          // 0..7
  const int lane = tid & 63;
  const int hi   = lane >> 5;
  const int l32  = lane & 31;
  const int iq   = wave & 1;          // q half (0/1)
  const int jk   = (wave >> 1) & 1;   // key half (0/1)
  const int sub  = wave >> 2;         // 32-key sub-window (0/1)
  const int xcd = blockIdx.x & 7;
  const int jj  = blockIdx.x >> 3;
  const int b   = xcd * 2 + (jj >> 5);
  const int qbase = (jj & 31) * 64 + iq * 32;
  const bf16* q0 = qb + (size_t)b * SDIM * HDIM;
  const bf16* k0 = kb + (size_t)b * SDIM * HDIM;
  const bf16* v0 = vT + (size_t)b * HDIM * SDIM;
  const int srow   = lane >> 3;            // 0..7
  const int schunk = (lane & 7) ^ srow;    // pre-swizzled source 16B chunk
  const int rswz   = (l32 & 7) << 4;       // read-side XOR (row&7)<<4

  // Q B-frags: lane holds Q[qbase+l32][c*16 + hi*8 .. +8]  (global, L2-hot)
  bf16x8 qf[4];
#pragma unroll
  for (int c = 0; c < 4; ++c)
    qf[c] = *(const bf16x8*)(q0 + (size_t)(qbase + l32) * HDIM + c * 16 + hi * 8);

  f32x16 O[2];
#pragma unroll
  for (int ht = 0; ht < 2; ++ht)
#pragma unroll
    for (int r = 0; r < 16; ++r) O[ht][r] = 0.f;
  float l_acc = 0.f;

  // Staging with 8 waves, 4 gl_lds each:
  // waves 0-3: K (half = (w>>1)&1, rows (w&1)*32..+32)
  // waves 4-7: V (half = (w>>1)&1, h-rows (w&1)*32..+32)
  #define STAGE(sidx, db) {                                                    \
    const int half_ = (wave >> 1) & 1;                                         \
    const int rb_   = (wave & 1) * 32;                                         \
    const int key0_ = half_ * 1024 + (sidx) * 64;                              \
    if (wave < 4) {                                                            \
      const bf16* gk = k0 + (size_t)(key0_ + rb_ + srow) * HDIM + schunk * 8;  \
      bf16* lk = &Kbuf[db][half_][rb_ * 64];                                   \
      _Pragma("unroll")                                                        \
      for (int j4 = 0; j4 < 4; ++j4)                                           \
        gl_lds16(gk + (size_t)j4 * 8 * HDIM, lk + j4 * 8 * 64);                \
    } else {                                                                   \
      const bf16* gv = v0 + (size_t)(rb_ + srow) * SDIM + key0_ + schunk * 8;  \
      bf16* lv = &Vbuf[db][half_][rb_ * 64];                                   \
      _Pragma("unroll")                                                        \
      for (int j4 = 0; j4 < 4; ++j4)                                           \
        gl_lds16(gv + (size_t)j4 * 8 * SDIM, lv + j4 * 8 * 64);                \
    }                                                                          \
  }

  STAGE(0, 0);
#pragma unroll 2
  for (int s = 0; s < 16; ++s) {
    __syncthreads();                       // buf[s&1] staged
    if (s + 1 < 16) STAGE(s + 1, (s + 1) & 1);
    const bf16* KB = &Kbuf[s & 1][jk][0];
    const bf16* VB = &Vbuf[s & 1][jk][0];

    // QK^T for this wave's 32-key sub-window (4 MFMAs)
    f32x16 st;
#pragma unroll
    for (int r = 0; r < 16; ++r) st[r] = 0.f;
    const int krow = sub * 32 + l32;
    __builtin_amdgcn_s_setprio(1);
#pragma unroll
    for (int c = 0; c < 4; ++c) {
      bf16x8 kf = *(const bf16x8*)((const char*)KB + krow * 128 +
                                   ((c * 32 + hi * 16) ^ rswz));
      st = __builtin_amdgcn_mfma_f32_32x32x16_bf16(kf, qf[c], st, 0, 0, 0);
    }
    __builtin_amdgcn_s_setprio(0);
    // lane holds P[key = sub*32 + (r&3)+8*(r>>2)+4*hi][q=l32], log2 units
    float p[16];
#pragma unroll
    for (int r = 0; r < 16; ++r) p[r] = EXP2F(st[r]);
    {
      float s0 = (p[0] + p[1]) + (p[2] + p[3]);
      float s1 = (p[4] + p[5]) + (p[6] + p[7]);
      float s2 = (p[8] + p[9]) + (p[10] + p[11]);
      float s3 = (p[12] + p[13]) + (p[14] + p[15]);
      l_acc += (s0 + s1) + (s2 + s3);
    }
    // in-register transpose: cvt_pk pairs, swap row halves across lane+-32.
    bf16x8 pa0, pa1;
    {
      unsigned u0 = cvtpk_bf16(p[0], p[1]);
      unsigned u1 = cvtpk_bf16(p[2], p[3]);
      unsigned u2 = cvtpk_bf16(p[4], p[5]);
      unsigned u3 = cvtpk_bf16(p[6], p[7]);
      asm("v_permlane32_swap_b32 %0, %1" : "+v"(u0), "+v"(u2));
      asm("v_permlane32_swap_b32 %0, %1" : "+v"(u1), "+v"(u3));
      union { u32x4 u; bf16x8 v; } f0;
      f0.u[0] = u0; f0.u[1] = u1; f0.u[2] = u2; f0.u[3] = u3;
      pa0 = f0.v;
      unsigned u4 = cvtpk_bf16(p[8],  p[9]);
      unsigned u5 = cvtpk_bf16(p[10], p[11]);
      unsigned u6 = cvtpk_bf16(p[12], p[13]);
      unsigned u7 = cvtpk_bf16(p[14], p[15]);
      asm("v_permlane32_swap_b32 %0, %1" : "+v"(u4), "+v"(u6));
      asm("v_permlane32_swap_b32 %0, %1" : "+v"(u5), "+v"(u7));
      union { u32x4 u; bf16x8 v; } f1;
      f1.u[0] = u4; f1.u[1] = u5; f1.u[2] = u6; f1.u[3] = u7;
      pa1 = f1.v;
    }
    // PV over the 32-key sub-window: O[q][h] += P[q][t] * V[t][h] (4 MFMAs)
    __builtin_amdgcn_s_setprio(1);
#pragma unroll
    for (int ht = 0; ht < 2; ++ht) {
      const int vrow = ht * 32 + l32;
      bf16x8 vf0 = *(const bf16x8*)((const char*)VB + vrow * 128 +
                                    ((sub * 64 + 0 * 32 + hi * 16) ^ rswz));
      O[ht] = __builtin_amdgcn_mfma_f32_32x32x16_bf16(pa0, vf0, O[ht], 0, 0, 0);
      bf16x8 vf1 = *(const bf16x8*)((const char*)VB + vrow * 128 +
                                    ((sub * 64 + 1 * 32 + hi * 16) ^ rswz));
      O[ht] = __builtin_amdgcn_mfma_f32_32x32x16_bf16(pa1, vf1, O[ht], 0, 0, 0);
    }
    __builtin_amdgcn_s_setprio(0);
  }

  // lane l and l+32 cover complementary key rows for the same q
  l_acc += __shfl_xor(l_acc, 32);

  // -------- 4-way cross-group combine through freed K/V LDS --------
  // grp 1..3 write partials: grp1 -> Kbuf[0] (16KB), grp2 -> Kbuf[1],
  // grp3 -> Vbuf[0]; l partials -> Vbuf[1]. grp0 reduces + stores.
  const int grp = wave >> 1;
  __syncthreads();                       // all waves done with K/V buffers
  if (grp != 0) {
    float* pb = (grp == 1) ? (float*)&Kbuf[0][0][0]
              : (grp == 2) ? (float*)&Kbuf[1][0][0]
                           : (float*)&Vbuf[0][0][0];
#pragma unroll
    for (int r = 0; r < 16; ++r) {
      const int qrow = (r & 3) + 8 * (r >> 2) + 4 * hi;
      pb[(iq * 32 + qrow) * 64 + 0 * 32 + l32] = O[0][r];
      pb[(iq * 32 + qrow) * 64 + 1 * 32 + l32] = O[1][r];
    }
    if (hi == 0)
      ((float*)&Vbuf[1][0][0])[(grp - 1) * 64 + iq * 32 + l32] = l_acc;
  }
  __syncthreads();
  if (grp == 0) {
    const float* p1 = (const float*)&Kbuf[0][0][0];
    const float* p2 = (const float*)&Kbuf[1][0][0];
    const float* p3 = (const float*)&Vbuf[0][0][0];
    const float* lp = (const float*)&Vbuf[1][0][0];
    const float lt = l_acc + lp[0 * 64 + iq * 32 + l32]
                   + lp[1 * 64 + iq * 32 + l32] + lp[2 * 64 + iq * 32 + l32];
    const float inv_own = 1.0f / lt;       // lane holds total l for q=l32
#pragma unroll
    for (int r = 0; r < 16; ++r) {
      const int qrow = (r & 3) + 8 * (r >> 2) + 4 * hi;
      const float inv = __shfl(inv_own, qrow);
#pragma unroll
      for (int ht = 0; ht < 2; ++ht) {
        const int idx = (iq * 32 + qrow) * 64 + ht * 32 + l32;
        const float val = (O[ht][r] + p1[idx] + p2[idx] + p3[idx]) * inv;
        out[((size_t)b * SDIM + qbase + qrow) * HDIM + ht * 32 + l32] = val;
      }
    }
  }
  #undef STAGE
}

// ---------------------------------------------------------------------------
extern "C" void kernel_launch(void* const* d_in, const int* in_sizes, int n_in,
                              void* d_out, int out_size, void* d_ws, size_t ws_size,
                              hipStream_t stream) {
  (void)in_sizes; (void)n_in; (void)out_size; (void)ws_size;
  const float* x  = (const float*)d_in[0];
  const int*   sl = (const int*)d_in[1];
  const float* Wq = (const float*)d_in[2];
  const float* Wk = (const float*)d_in[3];
  const float* Wv = (const float*)d_in[4];
  float* out = (float*)d_out;

  char* ws = (char*)d_ws;
  bf16* Wt = (bf16*)(ws);                              // 192 KB
  bf16* qb = (bf16*)(ws + (256 << 10));                // 4 MB
  bf16* kb = (bf16*)(ws + (256 << 10) + (4 << 20));    // 4 MB
  bf16* vT = (bf16*)(ws + (256 << 10) + (8 << 20));    // 4 MB ([B][64][S])

  wt_kernel  <<<24,  256, 0, stream>>>(Wq, Wk, Wv, Wt);
  proj_kernel<<<512, 256, 0, stream>>>(x, Wt, sl, qb, kb, vT);
  attn_kernel<<<512, 512, 0, stream>>>(qb, kb, vT, out);
}